// Round 4
// baseline (1111.185 us; speedup 1.0000x reference)
//
#include <hip/hip_runtime.h>
#include <math.h>

#define D     512
#define NCLS  10
#define GKB   32
#define NB    16
#define CHOLT 512
#define SSTR  20   // chol slab row stride (floats): 16B-aligned b128, 8-way quad spread

// ---------- meta: histogram + offsets + scatter (single block) ----------
__global__ __launch_bounds__(1024) void meta_kernel(const int* __restrict__ labels, int n,
                                                    int* __restrict__ counts,
                                                    int* __restrict__ offsets,
                                                    int* __restrict__ perm) {
    __shared__ int sc[NCLS], scur[NCLS], soff[NCLS + 1];
    int t = threadIdx.x;
    if (t < NCLS) { sc[t] = 0; scur[t] = 0; }
    __syncthreads();
    for (int i = t; i < n; i += 1024) atomicAdd(&sc[labels[i]], 1);
    __syncthreads();
    if (t == 0) {
        int a = 0;
        for (int c = 0; c < NCLS; ++c) { soff[c] = a; a += sc[c]; }
        soff[NCLS] = a;
    }
    __syncthreads();
    for (int i = t; i < n; i += 1024) {
        int l = labels[i];
        int pos = soff[l] + atomicAdd(&scur[l], 1);
        perm[pos] = i;
    }
    if (t < NCLS) { counts[t] = sc[t]; offsets[t] = soff[t]; }
}

// ---------- per-class grams: G[c] = sum_{i in class c} z_i z_i^T ----------
// 128x64 tile, 256 thr, 8x4 acc (VALU-bound: 32 fma per 3 b128).
// grid.x = 32 tiles (4 row-tiles x 8 col-tiles), grid.y = 20 jobs.
__global__ __launch_bounds__(256) void gram_kernel(const float* __restrict__ Z,
                                                   const float* __restrict__ Zb,
                                                   const int* __restrict__ offsets,
                                                   const int* __restrict__ counts,
                                                   const int* __restrict__ perm,
                                                   float* __restrict__ Gz,
                                                   float* __restrict__ Gzb) {
    const int job = blockIdx.y;
    const int tensor = job / NCLS;
    const int c = job % NCLS;
    const float* __restrict__ A = tensor ? Zb : Z;
    float* __restrict__ G = (tensor ? Gzb : Gz) + (size_t)c * D * D;
    const int off = offsets[c], cnt = counts[c];
    const int x0 = (blockIdx.x >> 3) * 128, y0 = (blockIdx.x & 7) * 64;

    __shared__ __align__(16) float As[GKB][128];   // 16KB
    __shared__ __align__(16) float Bs[GKB][64];    //  8KB

    const int t = threadIdx.x;
    const int tx = t & 15, tr = t >> 4;   // cols tx*4.., rows tr*8..
    float acc[8][4] = {};

    for (int r0 = 0; r0 < cnt; r0 += GKB) {
        // stage A tile: GKB rows x 128 cols = 1024 quads, coalesced
        #pragma unroll
        for (int it = 0; it < 4; ++it) {
            int q = t + 256 * it;
            int kr = q >> 5, cq = q & 31;
            int r = r0 + kr;
            float4 v = {0.f, 0.f, 0.f, 0.f};
            if (r < cnt) v = *(const float4*)&A[(size_t)perm[off + r] * D + x0 + 4 * cq];
            *(float4*)&As[kr][4 * cq] = v;
        }
        // stage B tile: GKB rows x 64 cols = 512 quads
        #pragma unroll
        for (int it = 0; it < 2; ++it) {
            int q = t + 256 * it;
            int kr = q >> 4, cq = q & 15;
            int r = r0 + kr;
            float4 v = {0.f, 0.f, 0.f, 0.f};
            if (r < cnt) v = *(const float4*)&A[(size_t)perm[off + r] * D + y0 + 4 * cq];
            *(float4*)&Bs[kr][4 * cq] = v;
        }
        __syncthreads();
        #pragma unroll
        for (int k = 0; k < GKB; ++k) {
            float4 a0 = *(const float4*)&As[k][tr * 8];
            float4 a1 = *(const float4*)&As[k][tr * 8 + 4];
            float4 bb = *(const float4*)&Bs[k][tx * 4];
            float av[8] = {a0.x, a0.y, a0.z, a0.w, a1.x, a1.y, a1.z, a1.w};
            float bv[4] = {bb.x, bb.y, bb.z, bb.w};
            #pragma unroll
            for (int s = 0; s < 8; ++s)
                #pragma unroll
                for (int jj = 0; jj < 4; ++jj)
                    acc[s][jj] = fmaf(av[s], bv[jj], acc[s][jj]);
        }
        __syncthreads();
    }
    #pragma unroll
    for (int s = 0; s < 8; ++s) {
        float4 o = {acc[s][0], acc[s][1], acc[s][2], acc[s][3]};
        *(float4*)&G[(size_t)(x0 + tr * 8 + s) * D + y0 + tx * 4] = o;
    }
}

// ---------- total grams (sum over classes) for the discrimn matrices ----------
__global__ __launch_bounds__(256) void gtot_kernel(const float* __restrict__ Gz,
                                                   const float* __restrict__ Gzb,
                                                   float* __restrict__ Tz,
                                                   float* __restrict__ Tzb) {
    const size_t DDv = (size_t)D * D;
    int q = blockIdx.x * 256 + threadIdx.x;   // float4 index, DD/4 = 65536
    if (q < 65536) {
        float4 sz = {0.f, 0.f, 0.f, 0.f}, sb = {0.f, 0.f, 0.f, 0.f};
        #pragma unroll
        for (int c = 0; c < NCLS; ++c) {
            float4 a = *(const float4*)&Gz[c * DDv + 4 * (size_t)q];
            float4 b = *(const float4*)&Gzb[c * DDv + 4 * (size_t)q];
            sz.x += a.x; sz.y += a.y; sz.z += a.z; sz.w += a.w;
            sb.x += b.x; sb.y += b.y; sb.z += b.z; sb.w += b.w;
        }
        *(float4*)&Tz[4 * (size_t)q] = sz;
        *(float4*)&Tzb[4 * (size_t)q] = sb;
    }
}

// ---------- batched Cholesky logdet, M built on the fly from grams ----------
// m=0/1: disc (Tz/Tzb); 2..11: compress Z; 12..21: compress Zb; 22..31: cross.
// Phase 1: left-looking Schur GEMM with LDS-staged double-buffered slabs (T14
// async split). Phase 2a: shuffle diag-block factor. 2b: parallel TRSM. 3: writeback.
__global__ __launch_bounds__(CHOLT) void chol_kernel(const float* __restrict__ Tz,
                                                     const float* __restrict__ Tzb,
                                                     const float* __restrict__ Gz,
                                                     const float* __restrict__ Gzb,
                                                     const int* __restrict__ counts,
                                                     float* __restrict__ Lout,
                                                     double* __restrict__ logdets, int n) {
    const int m = blockIdx.x;
    const size_t DDv = (size_t)D * D;
    float* __restrict__ A = Lout + (size_t)m * DDv;

    const float* g0; const float* g1 = nullptr;
    double scald;
    if (m == 0)      { g0 = Tz;  scald = (double)D / ((double)n * 0.5); }
    else if (m == 1) { g0 = Tzb; scald = (double)D / ((double)n * 0.5); }
    else if (m < 12) { int c = m - 2;  g0 = Gz  + (size_t)c * DDv;
                       scald = (double)D / (((double)counts[c] + 1e-8) * 0.5); }
    else if (m < 22) { int c = m - 12; g0 = Gzb + (size_t)c * DDv;
                       scald = (double)D / (((double)counts[c] + 1e-8) * 0.5); }
    else             { int c = m - 22; g0 = Gz + (size_t)c * DDv; g1 = Gzb + (size_t)c * DDv;
                       int cnt = counts[c];
                       scald = cnt ? (double)D / ((double)(2 * cnt) * 0.5) : 0.0; }
    const float scal = (float)scald;

    __shared__ __align__(16) float S[2][D * SSTR];   // 2 x 40KB slab double-buffer
    __shared__ float P[D * (NB + 1)];                // panel, stride 17
    __shared__ float invd[NB];
    __shared__ float diagAll[D];
    __shared__ double wpart[CHOLT / 64];
    const int t = threadIdx.x;
    const int il = t & 127, jg = t >> 7;
    const int srow = t >> 2, skq = (t & 3) * 4;      // staging: 4 lanes per row

    for (int b = 0; b < D / NB; ++b) {
        const int J0 = b * NB;
        const int R = D - J0;
        // ---- init acc = I + scal*G  (panel block: rows J0+i, cols J0+jg*4..+3)
        float acc[4][4];
        #pragma unroll
        for (int s2 = 0; s2 < 4; ++s2) {
            int i = il + 128 * s2;
            if (i < R) {
                size_t base = (size_t)(J0 + i) * D + J0 + jg * 4;
                float4 v = *(const float4*)(g0 + base);
                if (g1) {
                    float4 w = *(const float4*)(g1 + base);
                    v.x += w.x; v.y += w.y; v.z += w.z; v.w += w.w;
                }
                float gv[4] = {v.x, v.y, v.z, v.w};
                #pragma unroll
                for (int jj = 0; jj < 4; ++jj)
                    acc[s2][jj] = scal * gv[jj] + ((i == jg * 4 + jj) ? 1.f : 0.f);
            } else {
                #pragma unroll
                for (int jj = 0; jj < 4; ++jj) acc[s2][jj] = 0.f;
            }
        }
        // ---- phase 1: acc -= sum_{k<J0} L[J0+i][k] * L[J0+jg*4+jj][k]
        const int nslab = J0 >> 4;
        if (nslab) {
            float4 rg0, rg1, rg2, rg3;
#define SLOAD(kk) { \
            if (srow       < R) rg0 = *(const float4*)&A[(size_t)(J0 + srow      ) * D + (kk) + skq]; \
            if (srow + 128 < R) rg1 = *(const float4*)&A[(size_t)(J0 + srow + 128) * D + (kk) + skq]; \
            if (srow + 256 < R) rg2 = *(const float4*)&A[(size_t)(J0 + srow + 256) * D + (kk) + skq]; \
            if (srow + 384 < R) rg3 = *(const float4*)&A[(size_t)(J0 + srow + 384) * D + (kk) + skq]; }
#define SWRITE(Sb) { \
            if (srow       < R) *(float4*)&(Sb)[(srow      ) * SSTR + skq] = rg0; \
            if (srow + 128 < R) *(float4*)&(Sb)[(srow + 128) * SSTR + skq] = rg1; \
            if (srow + 256 < R) *(float4*)&(Sb)[(srow + 256) * SSTR + skq] = rg2; \
            if (srow + 384 < R) *(float4*)&(Sb)[(srow + 384) * SSTR + skq] = rg3; }
            SLOAD(0); SWRITE(S[0]); __syncthreads();
            int buf = 0;
            for (int ks = 0; ks < nslab; ++ks) {
                const bool more = (ks + 1 < nslab);
                if (more) SLOAD((ks + 1) << 4);          // issue early (T14)
                const float* Sb = &S[buf][0];
                #pragma unroll
                for (int k4 = 0; k4 < 4; ++k4) {
                    float4 bq0 = *(const float4*)&Sb[(jg * 4 + 0) * SSTR + 4 * k4];
                    float4 bq1 = *(const float4*)&Sb[(jg * 4 + 1) * SSTR + 4 * k4];
                    float4 bq2 = *(const float4*)&Sb[(jg * 4 + 2) * SSTR + 4 * k4];
                    float4 bq3 = *(const float4*)&Sb[(jg * 4 + 3) * SSTR + 4 * k4];
                    float bv[4][4] = {{bq0.x, bq0.y, bq0.z, bq0.w},
                                      {bq1.x, bq1.y, bq1.z, bq1.w},
                                      {bq2.x, bq2.y, bq2.z, bq2.w},
                                      {bq3.x, bq3.y, bq3.z, bq3.w}};
                    #pragma unroll
                    for (int s2 = 0; s2 < 4; ++s2) {
                        int i = il + 128 * s2;
                        if (i < R) {
                            float4 aq = *(const float4*)&Sb[i * SSTR + 4 * k4];
                            float av[4] = {aq.x, aq.y, aq.z, aq.w};
                            #pragma unroll
                            for (int jj = 0; jj < 4; ++jj)
                                #pragma unroll
                                for (int u = 0; u < 4; ++u)
                                    acc[s2][jj] = fmaf(-av[u], bv[jj][u], acc[s2][jj]);
                        }
                    }
                }
                if (more) SWRITE(S[buf ^ 1]);            // vmcnt wait lands here
                __syncthreads();
                buf ^= 1;
            }
#undef SLOAD
#undef SWRITE
        }
        __syncthreads();                 // P free (prev panel's phase-3 reads done)
        #pragma unroll
        for (int s2 = 0; s2 < 4; ++s2) {
            int i = il + 128 * s2;
            if (i < R)
                #pragma unroll
                for (int jj = 0; jj < 4; ++jj)
                    P[i * (NB + 1) + jg * 4 + jj] = acc[s2][jj];
        }
        __syncthreads();
        // ---- phase 2a: lanes 0..15 of wave 0 factor the 16x16 diag block in regs
        if (t < NB) {
            float r[NB];
            #pragma unroll
            for (int k = 0; k < NB; ++k) r[k] = P[t * (NB + 1) + k];
            #pragma unroll
            for (int j = 0; j < NB; ++j) {
                float pjj = __shfl(r[j], j, 64);
                float ljj = sqrtf(pjj);
                float inv = 1.0f / ljj;
                if (t == j) r[j] = ljj;
                else if (t > j) r[j] *= inv;          // r[j] = L[t][j]
                #pragma unroll
                for (int k2 = j + 1; k2 < NB; ++k2) {
                    float lkj = __shfl(r[j], k2, 64); // L[k2][j]
                    if (t >= k2) r[k2] -= r[j] * lkj;
                }
            }
            #pragma unroll
            for (int k = 0; k < NB; ++k) P[t * (NB + 1) + k] = r[k];
            diagAll[J0 + t] = r[t];
            invd[t] = 1.0f / r[t];
        }
        __syncthreads();
        // ---- phase 2b: parallel TRSM — row i solves L11 x^T = a^T (one row/thread)
        {
            int i = NB + t;
            if (i < R) {
                float x[NB];
                #pragma unroll
                for (int k = 0; k < NB; ++k) x[k] = P[i * (NB + 1) + k];
                #pragma unroll
                for (int j = 0; j < NB; ++j) {
                    float tj = x[j];
                    #pragma unroll
                    for (int k = 0; k < NB; ++k)
                        if (k < j) tj -= P[j * (NB + 1) + k] * x[k];  // uniform broadcast
                    x[j] = tj * invd[j];
                }
                #pragma unroll
                for (int k = 0; k < NB; ++k) P[i * (NB + 1) + k] = x[k];
            }
        }
        __syncthreads();
        // ---- phase 3: write panel back to Lout (upper junk never read)
        for (int e = t; e < R * NB; e += CHOLT) {
            int i = e >> 4, j = e & (NB - 1);
            A[(size_t)(J0 + i) * D + J0 + j] = P[i * (NB + 1) + j];
        }
        __syncthreads();
    }
    // ---- logdet = 2 * sum log(diag)
    double part = 0.0;
    for (int i = t; i < D; i += CHOLT) part += log((double)diagAll[i]);
    #pragma unroll
    for (int o = 32; o > 0; o >>= 1) part += __shfl_down(part, o, 64);
    if ((t & 63) == 0) wpart[t >> 6] = part;
    __syncthreads();
    if (t == 0) {
        double s2 = 0.0;
        for (int w = 0; w < CHOLT / 64; ++w) s2 += wpart[w];
        logdets[m] = 2.0 * s2;
    }
}

// ---------- final scalar combination (f64) ----------
__global__ void final_kernel(const double* __restrict__ logdets,
                             const int* __restrict__ counts, int n,
                             float* __restrict__ out) {
    if (threadIdx.x == 0 && blockIdx.x == 0) {
        double z_disc  = logdets[0] * 0.5;
        double zb_disc = logdets[1] * 0.5;
        double z_comp = 0.0, zb_comp = 0.0, sum_z = 0.0, sum_zb = 0.0, itemR = 0.0;
        for (int c = 0; c < NCLS; ++c) {
            double cnt = (double)counts[c];
            double zl  = (counts[c] == 0) ? 1.0 : logdets[2 + c];
            double zbl = (counts[c] == 0) ? 1.0 : logdets[12 + c];
            double scal = (cnt + 1e-8) / (2.0 * (double)n);
            z_comp  += scal * zl;
            zb_comp += scal * zbl;
            sum_z   += zl;
            sum_zb  += zbl;
            itemR   += logdets[22 + c] * 0.5;
        }
        double errD_ = (z_disc - z_comp) + (zb_disc - zb_comp)
                     + (itemR - 0.25 * sum_z - 0.25 * sum_zb);
        out[0] = (float)(-errD_);
        out[1] = (float)(-(z_disc - z_comp));
        out[2] = (float)(-(zb_disc - zb_comp));
        out[3] = (float)(-itemR + 0.25 * sum_z + 0.25 * sum_zb);
    }
}

extern "C" void kernel_launch(void* const* d_in, const int* in_sizes, int n_in,
                              void* d_out, int out_size, void* d_ws, size_t ws_size,
                              hipStream_t stream) {
    const float* Z      = (const float*)d_in[0];
    const float* Zb     = (const float*)d_in[1];
    const int*   labels = (const int*)d_in[2];
    const int n = in_sizes[2];
    float* out = (float*)d_out;

    const size_t DDv = (size_t)D * D;
    float*  Gz      = (float*)d_ws;                  // 10*DD
    float*  Gzb     = Gz + NCLS * DDv;               // 10*DD
    float*  Tz      = Gzb + NCLS * DDv;              // DD
    float*  Tzb     = Tz + DDv;                      // DD
    float*  Lout    = Tzb + DDv;                     // 32*DD
    double* logdets = (double*)(Lout + 32 * DDv);    // 8-aligned (54*DD*4 bytes)
    int*    counts  = (int*)(logdets + 32);
    int*    offsets = counts + NCLS;
    int*    perm    = offsets + NCLS;

    meta_kernel<<<1, 1024, 0, stream>>>(labels, n, counts, offsets, perm);
    dim3 ggrid(32, 20);
    gram_kernel<<<ggrid, 256, 0, stream>>>(Z, Zb, offsets, counts, perm, Gz, Gzb);
    gtot_kernel<<<256, 256, 0, stream>>>(Gz, Gzb, Tz, Tzb);
    chol_kernel<<<32, CHOLT, 0, stream>>>(Tz, Tzb, Gz, Gzb, counts, Lout, logdets, n);
    final_kernel<<<1, 64, 0, stream>>>(logdets, counts, n, out);
}

// Round 8
// 956.726 us; speedup vs baseline: 1.1614x; 1.1614x over previous
//
#include <hip/hip_runtime.h>
#include <math.h>

#define D     512
#define NCLS  10
#define GKB   32
#define NB    16
#define SSTR  20   // slab row stride (floats): b128-aligned, 8 lanes cover all 32 banks
#define PSTR  20   // panel row stride (floats): same property

// ---------- meta: histogram + offsets + scatter (single block) ----------
__global__ __launch_bounds__(1024) void meta_kernel(const int* __restrict__ labels, int n,
                                                    int* __restrict__ counts,
                                                    int* __restrict__ offsets,
                                                    int* __restrict__ perm) {
    __shared__ int sc[NCLS], scur[NCLS], soff[NCLS + 1];
    int t = threadIdx.x;
    if (t < NCLS) { sc[t] = 0; scur[t] = 0; }
    __syncthreads();
    for (int i = t; i < n; i += 1024) atomicAdd(&sc[labels[i]], 1);
    __syncthreads();
    if (t == 0) {
        int a = 0;
        for (int c = 0; c < NCLS; ++c) { soff[c] = a; a += sc[c]; }
        soff[NCLS] = a;
    }
    __syncthreads();
    for (int i = t; i < n; i += 1024) {
        int l = labels[i];
        int pos = soff[l] + atomicAdd(&scur[l], 1);
        perm[pos] = i;
    }
    if (t < NCLS) { counts[t] = sc[t]; offsets[t] = soff[t]; }
}

// ---------- per-class grams: G[c] = sum_{i in class c} z_i z_i^T ----------
__global__ __launch_bounds__(256) void gram_kernel(const float* __restrict__ Z,
                                                   const float* __restrict__ Zb,
                                                   const int* __restrict__ offsets,
                                                   const int* __restrict__ counts,
                                                   const int* __restrict__ perm,
                                                   float* __restrict__ Gz,
                                                   float* __restrict__ Gzb) {
    const int job = blockIdx.y;
    const int tensor = job / NCLS;
    const int c = job % NCLS;
    const float* __restrict__ A = tensor ? Zb : Z;
    float* __restrict__ G = (tensor ? Gzb : Gz) + (size_t)c * D * D;
    const int off = offsets[c], cnt = counts[c];
    const int x0 = (blockIdx.x >> 3) * 128, y0 = (blockIdx.x & 7) * 64;

    __shared__ __align__(16) float As[GKB][128];
    __shared__ __align__(16) float Bs[GKB][64];

    const int t = threadIdx.x;
    const int tx = t & 15, tr = t >> 4;
    float acc[8][4] = {};

    for (int r0 = 0; r0 < cnt; r0 += GKB) {
        #pragma unroll
        for (int it = 0; it < 4; ++it) {
            int q = t + 256 * it;
            int kr = q >> 5, cq = q & 31;
            int r = r0 + kr;
            float4 v = {0.f, 0.f, 0.f, 0.f};
            if (r < cnt) v = *(const float4*)&A[(size_t)perm[off + r] * D + x0 + 4 * cq];
            *(float4*)&As[kr][4 * cq] = v;
        }
        #pragma unroll
        for (int it = 0; it < 2; ++it) {
            int q = t + 256 * it;
            int kr = q >> 4, cq = q & 15;
            int r = r0 + kr;
            float4 v = {0.f, 0.f, 0.f, 0.f};
            if (r < cnt) v = *(const float4*)&A[(size_t)perm[off + r] * D + y0 + 4 * cq];
            *(float4*)&Bs[kr][4 * cq] = v;
        }
        __syncthreads();
        #pragma unroll
        for (int k = 0; k < GKB; ++k) {
            float4 a0 = *(const float4*)&As[k][tr * 8];
            float4 a1 = *(const float4*)&As[k][tr * 8 + 4];
            float4 bb = *(const float4*)&Bs[k][tx * 4];
            float av[8] = {a0.x, a0.y, a0.z, a0.w, a1.x, a1.y, a1.z, a1.w};
            float bv[4] = {bb.x, bb.y, bb.z, bb.w};
            #pragma unroll
            for (int s = 0; s < 8; ++s)
                #pragma unroll
                for (int jj = 0; jj < 4; ++jj)
                    acc[s][jj] = fmaf(av[s], bv[jj], acc[s][jj]);
        }
        __syncthreads();
    }
    #pragma unroll
    for (int s = 0; s < 8; ++s) {
        float4 o = {acc[s][0], acc[s][1], acc[s][2], acc[s][3]};
        *(float4*)&G[(size_t)(x0 + tr * 8 + s) * D + y0 + tx * 4] = o;
    }
}

// ---------- total grams (sum over classes) ----------
__global__ __launch_bounds__(256) void gtot_kernel(const float* __restrict__ Gz,
                                                   const float* __restrict__ Gzb,
                                                   float* __restrict__ Tz,
                                                   float* __restrict__ Tzb) {
    const size_t DDv = (size_t)D * D;
    int q = blockIdx.x * 256 + threadIdx.x;
    if (q < 65536) {
        float4 sz = {0.f, 0.f, 0.f, 0.f}, sb = {0.f, 0.f, 0.f, 0.f};
        #pragma unroll
        for (int c = 0; c < NCLS; ++c) {
            float4 a = *(const float4*)&Gz[c * DDv + 4 * (size_t)q];
            float4 b = *(const float4*)&Gzb[c * DDv + 4 * (size_t)q];
            sz.x += a.x; sz.y += a.y; sz.z += a.z; sz.w += a.w;
            sb.x += b.x; sb.y += b.y; sb.z += b.z; sb.w += b.w;
        }
        *(float4*)&Tz[4 * (size_t)q] = sz;
        *(float4*)&Tzb[4 * (size_t)q] = sb;
    }
}

// ---------- batched Cholesky logdet, k-split phase-1 (DS-pressure fix) ----------
// Thread map: il = t&127 (row base, rows il+128*s2), jg = t>>7 = K-QUADRANT
// (wave-uniform). Each thread: 4 rows x 16 cols over its 4 k-values per slab.
// Per slab/thread: 4 aq b128 + 16 uniform bq b128 + 256 FMA -> VALU-bound.
// Panel end: pairwise reduction over jg through the idle S buffers.
__global__ __launch_bounds__(512) void chol_kernel(const float* __restrict__ Tz,
                                                   const float* __restrict__ Tzb,
                                                   const float* __restrict__ Gz,
                                                   const float* __restrict__ Gzb,
                                                   const int* __restrict__ counts,
                                                   float* __restrict__ Lout,
                                                   double* __restrict__ logdets, int n) {
    const int m = blockIdx.x;
    const size_t DDv = (size_t)D * D;
    float* __restrict__ A = Lout + (size_t)m * DDv;

    const float* g0; const float* g1 = nullptr;
    double scald;
    if (m == 0)      { g0 = Tz;  scald = (double)D / ((double)n * 0.5); }
    else if (m == 1) { g0 = Tzb; scald = (double)D / ((double)n * 0.5); }
    else if (m < 12) { int c = m - 2;  g0 = Gz  + (size_t)c * DDv;
                       scald = (double)D / (((double)counts[c] + 1e-8) * 0.5); }
    else if (m < 22) { int c = m - 12; g0 = Gzb + (size_t)c * DDv;
                       scald = (double)D / (((double)counts[c] + 1e-8) * 0.5); }
    else             { int c = m - 22; g0 = Gz + (size_t)c * DDv; g1 = Gzb + (size_t)c * DDv;
                       int cnt = counts[c];
                       scald = cnt ? (double)D / ((double)(2 * cnt) * 0.5) : 0.0; }
    const float scal = (float)scald;

    __shared__ __align__(16) float S[2][D * SSTR];   // 2 x 40KB
    __shared__ __align__(16) float P[D * PSTR];      // 40KB
    __shared__ float invd[NB];
    __shared__ float diagAll[D];
    __shared__ double wpart[8];
    const int t = threadIdx.x;
    const int il = t & 127, jg = t >> 7;             // jg = k-quadrant (wave-uniform)
    const int srow = t >> 2, skq = (t & 3) * 4;      // staging: 4 lanes per row

    for (int b = 0; b < D / NB; ++b) {
        const int J0 = b * NB;
        const int R = D - J0;
        // ---- init acc = I + scal*G (only jg==0 carries it; others start at 0)
        float acc[4][16];
        #pragma unroll
        for (int s2 = 0; s2 < 4; ++s2)
            #pragma unroll
            for (int j = 0; j < 16; ++j) acc[s2][j] = 0.f;
        if (jg == 0) {
            #pragma unroll
            for (int s2 = 0; s2 < 4; ++s2) {
                int i = il + 128 * s2;
                if (i < R) {
                    size_t base = (size_t)(J0 + i) * D + J0;
                    #pragma unroll
                    for (int q = 0; q < 4; ++q) {
                        float4 v = *(const float4*)(g0 + base + 4 * q);
                        if (g1) {
                            float4 w = *(const float4*)(g1 + base + 4 * q);
                            v.x += w.x; v.y += w.y; v.z += w.z; v.w += w.w;
                        }
                        float gv[4] = {v.x, v.y, v.z, v.w};
                        #pragma unroll
                        for (int u = 0; u < 4; ++u)
                            acc[s2][4 * q + u] = scal * gv[u] + ((i == 4 * q + u) ? 1.f : 0.f);
                    }
                }
            }
        }
        // ---- phase 1: acc -= sum over this thread's k-quadrant of each slab
        const int nslab = J0 >> 4;
        if (nslab) {
            float4 rg0, rg1, rg2, rg3;
#define SLOAD(kk) { \
            if (srow       < R) rg0 = *(const float4*)&A[(size_t)(J0 + srow      ) * D + (kk) + skq]; \
            if (srow + 128 < R) rg1 = *(const float4*)&A[(size_t)(J0 + srow + 128) * D + (kk) + skq]; \
            if (srow + 256 < R) rg2 = *(const float4*)&A[(size_t)(J0 + srow + 256) * D + (kk) + skq]; \
            if (srow + 384 < R) rg3 = *(const float4*)&A[(size_t)(J0 + srow + 384) * D + (kk) + skq]; }
#define SWRITE(Sb) { \
            if (srow       < R) *(float4*)&(Sb)[(srow      ) * SSTR + skq] = rg0; \
            if (srow + 128 < R) *(float4*)&(Sb)[(srow + 128) * SSTR + skq] = rg1; \
            if (srow + 256 < R) *(float4*)&(Sb)[(srow + 256) * SSTR + skq] = rg2; \
            if (srow + 384 < R) *(float4*)&(Sb)[(srow + 384) * SSTR + skq] = rg3; }
            SLOAD(0); SWRITE(S[0]); __syncthreads();
            int buf = 0;
            for (int ks = 0; ks < nslab; ++ks) {
                const bool more = (ks + 1 < nslab);
                if (more) SLOAD((ks + 1) << 4);      // issue early (T14)
                const float* Sb = &S[buf][0];
                if (il < R) {
                    float4 bq[16];
                    #pragma unroll
                    for (int j = 0; j < 16; ++j)
                        bq[j] = *(const float4*)&Sb[j * SSTR + jg * 4];   // uniform
                    #pragma unroll
                    for (int s2 = 0; s2 < 4; ++s2) {
                        int i = il + 128 * s2;
                        if (i < R) {
                            float4 aq = *(const float4*)&Sb[i * SSTR + jg * 4];
                            float av[4] = {aq.x, aq.y, aq.z, aq.w};
                            #pragma unroll
                            for (int j = 0; j < 16; ++j) {
                                float bv[4] = {bq[j].x, bq[j].y, bq[j].z, bq[j].w};
                                #pragma unroll
                                for (int u = 0; u < 4; ++u)
                                    acc[s2][j] = fmaf(-av[u], bv[u], acc[s2][j]);
                            }
                        }
                    }
                }
                if (more) SWRITE(S[buf ^ 1]);        // vmcnt wait lands here
                __syncthreads();
                buf ^= 1;
            }
#undef SLOAD
#undef SWRITE
        }
        // ---- reduction over jg -> P (pairwise through idle S buffers)
        {
            float* S0 = &S[0][0];
            float* S1 = &S[1][0];
#define DUMP(Sx) { \
            _Pragma("unroll") for (int s2 = 0; s2 < 4; ++s2) { int i = il + 128 * s2; \
              if (i < R) { _Pragma("unroll") for (int q = 0; q < 4; ++q) { \
                float4 o = {acc[s2][4*q], acc[s2][4*q+1], acc[s2][4*q+2], acc[s2][4*q+3]}; \
                *(float4*)&(Sx)[i * SSTR + 4 * q] = o; } } } }
#define ADDF(Sx) { \
            _Pragma("unroll") for (int s2 = 0; s2 < 4; ++s2) { int i = il + 128 * s2; \
              if (i < R) { _Pragma("unroll") for (int q = 0; q < 4; ++q) { \
                float4 v = *(const float4*)&(Sx)[i * SSTR + 4 * q]; \
                acc[s2][4*q] += v.x; acc[s2][4*q+1] += v.y; \
                acc[s2][4*q+2] += v.z; acc[s2][4*q+3] += v.w; } } } }
            if (jg == 1) DUMP(S0)
            else if (jg == 3) DUMP(S1)
            __syncthreads();
            if (jg == 0) ADDF(S0)
            else if (jg == 2) ADDF(S1)
            __syncthreads();
            if (jg == 2) DUMP(S0)
            __syncthreads();
            if (jg == 0) {
                ADDF(S0)
                #pragma unroll
                for (int s2 = 0; s2 < 4; ++s2) {
                    int i = il + 128 * s2;
                    if (i < R) {
                        #pragma unroll
                        for (int q = 0; q < 4; ++q) {
                            float4 o = {acc[s2][4*q], acc[s2][4*q+1],
                                        acc[s2][4*q+2], acc[s2][4*q+3]};
                            *(float4*)&P[i * PSTR + 4 * q] = o;
                        }
                    }
                }
            }
            __syncthreads();
#undef DUMP
#undef ADDF
        }
        // ---- phase 2a: lanes 0..15 of wave 0 factor the 16x16 diag block in regs
        if (t < NB) {
            float r[NB];
            #pragma unroll
            for (int k = 0; k < NB; ++k) r[k] = P[t * PSTR + k];
            #pragma unroll
            for (int j = 0; j < NB; ++j) {
                float pjj = __shfl(r[j], j, 64);
                float ljj = sqrtf(pjj);
                float inv = 1.0f / ljj;
                if (t == j) r[j] = ljj;
                else if (t > j) r[j] *= inv;          // r[j] = L[t][j]
                #pragma unroll
                for (int k2 = j + 1; k2 < NB; ++k2) {
                    float lkj = __shfl(r[j], k2, 64);
                    if (t >= k2) r[k2] -= r[j] * lkj;
                }
            }
            #pragma unroll
            for (int k = 0; k < NB; ++k) P[t * PSTR + k] = r[k];
            diagAll[J0 + t] = r[t];
            invd[t] = 1.0f / r[t];
        }
        __syncthreads();
        // ---- phase 2b: parallel TRSM, b128 row reads (uniform), static unroll
        {
            int i2 = NB + t;
            if (i2 < R) {
                float x[16];
                #pragma unroll
                for (int q = 0; q < 4; ++q) {
                    float4 v = *(const float4*)&P[i2 * PSTR + 4 * q];
                    x[4*q] = v.x; x[4*q+1] = v.y; x[4*q+2] = v.z; x[4*q+3] = v.w;
                }
                #pragma unroll
                for (int j = 0; j < 16; ++j) {
                    float tj = x[j];
                    #pragma unroll
                    for (int q = 0; q < 4; ++q) {
                        if (4 * q < j) {
                            float4 Lv = *(const float4*)&P[j * PSTR + 4 * q];
                            float Lf[4] = {Lv.x, Lv.y, Lv.z, Lv.w};
                            #pragma unroll
                            for (int u = 0; u < 4; ++u)
                                if (4 * q + u < j) tj -= Lf[u] * x[4 * q + u];
                        }
                    }
                    x[j] = tj * invd[j];
                }
                #pragma unroll
                for (int q = 0; q < 4; ++q) {
                    float4 o = {x[4*q], x[4*q+1], x[4*q+2], x[4*q+3]};
                    *(float4*)&P[i2 * PSTR + 4 * q] = o;
                }
            }
        }
        __syncthreads();
        // ---- phase 3: write panel back to Lout (one row per thread, b128)
        if (t < R) {
            #pragma unroll
            for (int q = 0; q < 4; ++q) {
                float4 v = *(const float4*)&P[t * PSTR + 4 * q];
                *(float4*)&A[(size_t)(J0 + t) * D + J0 + 4 * q] = v;
            }
        }
        __syncthreads();
    }
    // ---- logdet = 2 * sum log(diag)
    double part = 0.0;
    for (int i = t; i < D; i += 512) part += log((double)diagAll[i]);
    #pragma unroll
    for (int o = 32; o > 0; o >>= 1) part += __shfl_down(part, o, 64);
    if ((t & 63) == 0) wpart[t >> 6] = part;
    __syncthreads();
    if (t == 0) {
        double s2 = 0.0;
        for (int w = 0; w < 8; ++w) s2 += wpart[w];
        logdets[m] = 2.0 * s2;
    }
}

// ---------- final scalar combination (f64) ----------
__global__ void final_kernel(const double* __restrict__ logdets,
                             const int* __restrict__ counts, int n,
                             float* __restrict__ out) {
    if (threadIdx.x == 0 && blockIdx.x == 0) {
        double z_disc  = logdets[0] * 0.5;
        double zb_disc = logdets[1] * 0.5;
        double z_comp = 0.0, zb_comp = 0.0, sum_z = 0.0, sum_zb = 0.0, itemR = 0.0;
        for (int c = 0; c < NCLS; ++c) {
            double cnt = (double)counts[c];
            double zl  = (counts[c] == 0) ? 1.0 : logdets[2 + c];
            double zbl = (counts[c] == 0) ? 1.0 : logdets[12 + c];
            double scal = (cnt + 1e-8) / (2.0 * (double)n);
            z_comp  += scal * zl;
            zb_comp += scal * zbl;
            sum_z   += zl;
            sum_zb  += zbl;
            itemR   += logdets[22 + c] * 0.5;
        }
        double errD_ = (z_disc - z_comp) + (zb_disc - zb_comp)
                     + (itemR - 0.25 * sum_z - 0.25 * sum_zb);
        out[0] = (float)(-errD_);
        out[1] = (float)(-(z_disc - z_comp));
        out[2] = (float)(-(zb_disc - zb_comp));
        out[3] = (float)(-itemR + 0.25 * sum_z + 0.25 * sum_zb);
    }
}

extern "C" void kernel_launch(void* const* d_in, const int* in_sizes, int n_in,
                              void* d_out, int out_size, void* d_ws, size_t ws_size,
                              hipStream_t stream) {
    const float* Z      = (const float*)d_in[0];
    const float* Zb     = (const float*)d_in[1];
    const int*   labels = (const int*)d_in[2];
    const int n = in_sizes[2];
    float* out = (float*)d_out;

    const size_t DDv = (size_t)D * D;
    float*  Gz      = (float*)d_ws;                  // 10*DD
    float*  Gzb     = Gz + NCLS * DDv;               // 10*DD
    float*  Tz      = Gzb + NCLS * DDv;              // DD
    float*  Tzb     = Tz + DDv;                      // DD
    float*  Lout    = Tzb + DDv;                     // 32*DD
    double* logdets = (double*)(Lout + 32 * DDv);
    int*    counts  = (int*)(logdets + 32);
    int*    offsets = counts + NCLS;
    int*    perm    = offsets + NCLS;

    meta_kernel<<<1, 1024, 0, stream>>>(labels, n, counts, offsets, perm);
    dim3 ggrid(32, 20);
    gram_kernel<<<ggrid, 256, 0, stream>>>(Z, Zb, offsets, counts, perm, Gz, Gzb);
    gtot_kernel<<<256, 256, 0, stream>>>(Gz, Gzb, Tz, Tzb);
    chol_kernel<<<32, 512, 0, stream>>>(Tz, Tzb, Gz, Gzb, counts, Lout, logdets, n);
    final_kernel<<<1, 64, 0, stream>>>(logdets, counts, n, out);
}